// Round 4
// baseline (9040.327 us; speedup 1.0000x reference)
//
#include <hip/hip_runtime.h>
#include <hip/hip_bf16.h>
#include <math.h>

// Shapes (fixed): B=2 N=4 G=2 Ck=64 Cv=512 H=W=64 HW=4096 L=256 TOPL=64 Cin=1152 BN=8 BNG=16

typedef __attribute__((ext_vector_type(8))) short bf16x8;
typedef __attribute__((ext_vector_type(4))) float f32x4;
typedef __attribute__((ext_vector_type(16))) float f32x16;

static __device__ __forceinline__ short f2b(float f){
  __hip_bfloat16 h = __float2bfloat16(f);
  short s; __builtin_memcpy(&s, &h, 2); return s;
}
static __device__ __forceinline__ unsigned pack2(float lo, float hi){
  return (unsigned)(unsigned short)f2b(lo) | ((unsigned)(unsigned short)f2b(hi) << 16);
}
static __device__ __forceinline__ float b2f(unsigned short u){
  unsigned v = ((unsigned)u) << 16; float f; __builtin_memcpy(&f, &v, 4); return f;
}

static __device__ __forceinline__ float wred_max(float v){
  #pragma unroll
  for (int off = 32; off > 0; off >>= 1) v = fmaxf(v, __shfl_xor(v, off));
  return v;
}
static __device__ __forceinline__ float wred_sum(float v){
  #pragma unroll
  for (int off = 32; off > 0; off >>= 1) v += __shfl_xor(v, off);
  return v;
}

#define FMA16(X0,X1,X2,X3,KV) \
  acc[0]+=X0.x*KV; acc[1]+=X0.y*KV; acc[2]+=X0.z*KV; acc[3]+=X0.w*KV; \
  acc[4]+=X1.x*KV; acc[5]+=X1.y*KV; acc[6]+=X1.z*KV; acc[7]+=X1.w*KV; \
  acc[8]+=X2.x*KV; acc[9]+=X2.y*KV; acc[10]+=X2.z*KV; acc[11]+=X2.w*KV; \
  acc[12]+=X3.x*KV; acc[13]+=X3.y*KV; acc[14]+=X3.z*KV; acc[15]+=X3.w*KV;

// ---------------- prep kernels ----------------

// xT[b][hw][k] = qk[b][k][hw]; invn[b][hw] = 1/(||x||+1e-6)
__global__ void k_prep_x(const float* __restrict__ qk, float* __restrict__ xT, float* __restrict__ invn){
  int idx = blockIdx.x*256 + threadIdx.x;   // 8192 = B*HW
  int b = idx >> 12, hw = idx & 4095;
  float v[64]; float ss = 0.f;
  #pragma unroll
  for (int k=0;k<64;k++){ v[k] = qk[((size_t)b*64 + k)*4096 + hw]; ss += v[k]*v[k]; }
  invn[idx] = 1.f/(sqrtf(ss) + 1e-6f);
  #pragma unroll
  for (int k=0;k<64;k++) xT[(size_t)idx*64 + k] = v[k];
}

// kn0 = l2norm(kappa0) over k
__global__ void k_init_kn(const float* __restrict__ kappa0, float* __restrict__ kn){
  int bng = blockIdx.x; int l = threadIdx.x;   // 16 x 256
  float ss = 0.f;
  #pragma unroll 4
  for (int k=0;k<64;k++){ float v = kappa0[((size_t)bng*64 + k)*256 + l]; ss += v*v; }
  float inv = 1.f/(sqrtf(ss) + 1e-6f);
  #pragma unroll 4
  for (int k=0;k<64;k++) kn[((size_t)bng*64 + k)*256 + l] = kappa0[((size_t)bng*64 + k)*256 + l]*inv;
}

// Wt[((((cvb*72+cb)*9 + r)*2 + kh)*64 + cvl)*8 + j] = W[cvb*64+cvl][cb*16+kh*8+j][r]
__global__ void k_prep_wt(const float* __restrict__ Wsrc, short* __restrict__ Wt){
  int t = blockIdx.x*256 + threadIdx.x;   // 5,308,416
  int j = t & 7;
  int cvl = (t >> 3) & 63;
  int kh = (t >> 9) & 1;
  int rest = t >> 10;
  int r = rest % 9;
  int tile = rest / 9;
  int cb = tile % 72;
  int cvb = tile / 72;
  int cv = cvb*64 + cvl;
  int cin = cb*16 + kh*8 + j;
  Wt[t] = f2b(Wsrc[((size_t)cv*1152 + cin)*9 + r]);
}

// fin32 pair layout: fin32[bn*576*4096 + p*4096 + hw] = bf16 channels (2p, 2p+1); pairs [256,512) = qv
__global__ void k_qv_fin(const float* __restrict__ qv, unsigned* __restrict__ fin32){
  int t = blockIdx.x*256 + threadIdx.x;   // 8 * 2^20
  int bn = t >> 20;
  int rem = t & 1048575;
  int p = rem >> 12;
  int hw = rem & 4095;
  int b = bn >> 2;
  float lo = qv[((size_t)b*512 + 2*p)*4096 + hw];
  float hi = qv[((size_t)b*512 + 2*p + 1)*4096 + hw];
  fin32[(size_t)bn*2359296 + (size_t)(256 + p)*4096 + hw] = pack2(lo, hi);
}

// qvm fp32 -> bf16 (same layout)
__global__ void k_qvm16(const float* __restrict__ q, unsigned* __restrict__ o){
  int t = blockIdx.x*256 + threadIdx.x;   // 4,194,304
  float4 v = *(const float4*)(q + (size_t)t*4);
  o[(size_t)t*2]   = pack2(v.x, v.y);
  o[(size_t)t*2+1] = pack2(v.z, v.w);
}

// ---------------- fused EM iteration ----------------
// k_em: (optional sww weights) + zz softmax + kappa/zita partials. grid 256 = 8 bn * 32 ch, 512 thr.
// d = x . kn computed once; sww reuses it via s = d*invn.
__global__ __launch_bounds__(512) void k_em(const float* __restrict__ xT, const float* __restrict__ kn,
                                            const float* __restrict__ masks, const float* __restrict__ invn,
                                            float* __restrict__ kpart, float* __restrict__ zpart,
                                            short* __restrict__ zz16, int first, int last){
  int blk = blockIdx.x;
  int bn = blk >> 5, ch = blk & 31;
  int b = bn >> 2;
  int t = threadIdx.x;
  int g = t >> 8, l = t & 255;
  int lane = t & 63, wid = t >> 6;
  int bng = bn*2 + g;
  __shared__ float xs_d[64][17];
  __shared__ float xs_t[16][68];
  __shared__ float redA[16][8];
  __shared__ float redB[16][8];
  __shared__ float redC[16][8];
  float kp[64];
  #pragma unroll
  for (int k=0;k<64;k++) kp[k]=0.f;
  float zs = 0.f;
  const float* knp = kn + (size_t)bng*16384 + l;
  for (int st=0; st<8; st++){
    int hw0 = ch*128 + st*16;
    __syncthreads();
    if (t < 256){
      int px = t >> 4, kq = t & 15;
      float4 xv = *(const float4*)&xT[((size_t)b*4096 + hw0 + px)*64 + kq*4];
      xs_d[kq*4+0][px]=xv.x; xs_d[kq*4+1][px]=xv.y; xs_d[kq*4+2][px]=xv.z; xs_d[kq*4+3][px]=xv.w;
      *(float4*)&xs_t[px][kq*4] = xv;
    }
    __syncthreads();
    float acc[16];
    #pragma unroll
    for (int p=0;p<16;p++) acc[p]=0.f;
    #pragma unroll 2
    for (int k=0;k<64;k++){
      float knv = knp[k*256];
      float4 x0 = *(const float4*)&xs_d[k][0];
      float4 x1 = *(const float4*)&xs_d[k][4];
      float4 x2 = *(const float4*)&xs_d[k][8];
      float4 x3 = *(const float4*)&xs_d[k][12];
      FMA16(x0,x1,x2,x3,knv)
    }
    // phase1: per-px wave maxes
    #pragma unroll
    for (int p=0;p<16;p++){
      float m = wred_max(acc[p]);
      if (lane==p) redA[p][wid] = m;
    }
    __syncthreads();
    // phase2: exps + wave sums
    #pragma unroll
    for (int p=0;p<16;p++){
      float4 mA0 = *(const float4*)&redA[p][0];
      float4 mA1 = *(const float4*)&redA[p][4];
      float m0 = fmaxf(fmaxf(mA0.x,mA0.y),fmaxf(mA0.z,mA0.w));
      float m1 = fmaxf(fmaxf(mA1.x,mA1.y),fmaxf(mA1.z,mA1.w));
      float Mg = g ? m1 : m0;
      if (!first){
        float M2 = fmaxf(m0, m1);
        float iv = invn[(size_t)b*4096 + hw0 + p];
        float es = __expf((acc[p]-M2)*iv*20.f);
        float sw = wred_sum(es);
        if (lane==p) redB[p][wid] = sw;
      }
      float ez = __expf((acc[p]-Mg)*20.f);
      float sz = wred_sum(ez);
      if (lane==p) redC[p][wid] = sz;
      acc[p] = ez;
    }
    __syncthreads();
    // phase3: weights, normalize, kappa partial accumulate
    #pragma unroll
    for (int p=0;p<16;p++){
      float4 c0 = *(const float4*)&redC[p][g*4];
      float Zg = c0.x+c0.y+c0.z+c0.w;
      float mval = masks[(size_t)bng*4096 + hw0 + p];
      float w;
      if (first) w = mval;
      else {
        float4 b0 = *(const float4*)&redB[p][0];
        float4 b1 = *(const float4*)&redB[p][4];
        float S0 = b0.x+b0.y+b0.z+b0.w, S1 = b1.x+b1.y+b1.z+b1.w;
        float Sg = g ? S1 : S0;
        w = mval * (1.f - Sg/(S0+S1));
      }
      float zv = acc[p] / Zg * w;
      zs += zv;
      if (last) zz16[((size_t)bng*4096 + hw0 + p)*256 + l] = f2b(zv);
      #pragma unroll
      for (int k4=0;k4<16;k4++){
        float4 xv = *(const float4*)&xs_t[p][k4*4];
        kp[k4*4+0] += xv.x*zv; kp[k4*4+1] += xv.y*zv;
        kp[k4*4+2] += xv.z*zv; kp[k4*4+3] += xv.w*zv;
      }
    }
  }
  #pragma unroll
  for (int k=0;k<64;k++)
    kpart[(((size_t)bng*32 + ch)*64 + k)*256 + l] = kp[k];
  zpart[((size_t)bng*32 + ch)*256 + l] = zs;
}

// finalize zita, kappa, kn.  grid 64 = 16 bng * 4 lq, 256 thr
__global__ __launch_bounds__(256) void k_fin(const float* __restrict__ kpart, const float* __restrict__ zpart,
                                             const float* __restrict__ kappa0, const float* __restrict__ zita0,
                                             float* __restrict__ kn, float* __restrict__ zita){
  int bng = blockIdx.x >> 2, lq = blockIdx.x & 3;
  int t = threadIdx.x; int lo = t & 63, kq = t >> 6;
  int l = lq*64 + lo;
  float z0 = zita0[bng*256 + l];
  float zs = z0;
  #pragma unroll 4
  for (int ch=0; ch<32; ch++) zs += zpart[((size_t)bng*32 + ch)*256 + l];
  if (kq==0) zita[bng*256 + l] = zs;
  float inv = 1.f/zs;
  float kap[16]; float ss = 0.f;
  #pragma unroll
  for (int j=0;j<16;j++){
    int k = kq*16 + j;
    float a = z0 * kappa0[((size_t)bng*64 + k)*256 + l];
    #pragma unroll 4
    for (int ch=0; ch<32; ch++) a += kpart[(((size_t)bng*32 + ch)*64 + k)*256 + l];
    float kv = a*inv; kap[j] = kv; ss += kv*kv;
  }
  __shared__ float ssr[4][64];
  ssr[kq][lo] = ss;
  __syncthreads();
  float tot = ssr[0][lo]+ssr[1][lo]+ssr[2][lo]+ssr[3][lo];
  float ninv = 1.f/(sqrtf(tot) + 1e-6f);
  #pragma unroll
  for (int j=0;j<16;j++) kn[((size_t)bng*64 + kq*16 + j)*256 + l] = kap[j]*ninv;
}

// affinity softmax -> paff16 bf16 [bn][hw][g*256+l]. grid 256 = 8 bn * 32 ch, 512 thr
__global__ __launch_bounds__(512) void k_aff(const float* __restrict__ xT, const float* __restrict__ kn,
                                             const float* __restrict__ invn, short* __restrict__ paff16){
  int blk = blockIdx.x;
  int bn = blk >> 5, ch = blk & 31;
  int b = bn >> 2;
  int t = threadIdx.x;
  int g = t >> 8, l = t & 255;
  int lane = t & 63, wid = t >> 6;
  int bng = bn*2 + g;
  __shared__ float xs_d[64][17];
  __shared__ float redA[16][8];
  __shared__ float redB[16][8];
  const float* knp = kn + (size_t)bng*16384 + l;
  for (int st=0; st<8; st++){
    int hw0 = ch*128 + st*16;
    __syncthreads();
    if (t < 256){
      int px = t >> 4, kq = t & 15;
      float4 xv = *(const float4*)&xT[((size_t)b*4096 + hw0 + px)*64 + kq*4];
      xs_d[kq*4+0][px]=xv.x; xs_d[kq*4+1][px]=xv.y; xs_d[kq*4+2][px]=xv.z; xs_d[kq*4+3][px]=xv.w;
    }
    __syncthreads();
    float acc[16];
    #pragma unroll
    for (int p=0;p<16;p++) acc[p]=0.f;
    #pragma unroll 2
    for (int k=0;k<64;k++){
      float knv = knp[k*256];
      float4 x0 = *(const float4*)&xs_d[k][0];
      float4 x1 = *(const float4*)&xs_d[k][4];
      float4 x2 = *(const float4*)&xs_d[k][8];
      float4 x3 = *(const float4*)&xs_d[k][12];
      FMA16(x0,x1,x2,x3,knv)
    }
    #pragma unroll
    for (int p=0;p<16;p++){
      float m = wred_max(acc[p]);
      if (lane==p) redA[p][wid] = m;
    }
    __syncthreads();
    #pragma unroll
    for (int p=0;p<16;p++){
      float4 mA0 = *(const float4*)&redA[p][0];
      float4 mA1 = *(const float4*)&redA[p][4];
      float M2 = fmaxf(fmaxf(fmaxf(mA0.x,mA0.y),fmaxf(mA0.z,mA0.w)),
                       fmaxf(fmaxf(mA1.x,mA1.y),fmaxf(mA1.z,mA1.w)));
      float iv = invn[(size_t)b*4096 + hw0 + p];
      float e = __expf((acc[p]-M2)*iv*20.f);
      float s = wred_sum(e);
      if (lane==p) redB[p][wid] = s;
      acc[p] = e;
    }
    __syncthreads();
    #pragma unroll
    for (int p=0;p<16;p++){
      float4 b0 = *(const float4*)&redB[p][0];
      float4 b1 = *(const float4*)&redB[p][4];
      float S = b0.x+b0.y+b0.z+b0.w + b1.x+b1.y+b1.z+b1.w;
      paff16[((size_t)bn*4096 + hw0 + p)*512 + t] = f2b(acc[p]/S);
    }
  }
}

// ---------------- top-k / S channels ----------------

static __device__ __forceinline__ float topk_cum(float va, float vb, float vc, float vd, int lane){
  float run = 0.f, cme = 0.f;
  #pragma unroll 2
  for (int tt=0; tt<64; tt++){
    float m = fmaxf(fmaxf(va,vb), fmaxf(vc,vd));
    float wm = wred_max(m);
    run += wm;
    if (lane == tt) cme = run;
    unsigned long long ball = __ballot(m == wm);
    int wl = __ffsll(ball) - 1;
    if (lane == wl){
      if (va == wm) va = -1.f;
      else if (vb == wm) vb = -1.f;
      else if (vc == wm) vc = -1.f;
      else vd = -1.f;
    }
  }
  return cme;
}

__global__ __launch_bounds__(256) void k_topk(const short* __restrict__ paff16, unsigned* __restrict__ fin32){
  int wid = threadIdx.x >> 6, lane = threadIdx.x & 63;
  int px = blockIdx.x*4 + wid;           // 32768 pixels
  int bn = px >> 12, hw = px & 4095;
  const unsigned short* row = (const unsigned short*)paff16 + (size_t)px*512;
  ushort4 u0 = *(const ushort4*)(row + lane*4);
  ushort4 u1 = *(const ushort4*)(row + 256 + lane*4);
  float c0 = topk_cum(b2f(u0.x), b2f(u0.y), b2f(u0.z), b2f(u0.w), lane);
  float c1 = topk_cum(b2f(u1.x), b2f(u1.y), b2f(u1.z), b2f(u1.w), lane);
  float sf = c0/(c0+c1);
  float sf2 = __shfl_down(sf, 1);
  if (!(lane & 1)){
    size_t base = (size_t)bn*2359296;
    fin32[base + (size_t)(512 + (lane>>1))*4096 + hw] = pack2(sf, sf2);
    fin32[base + (size_t)(544 + (lane>>1))*4096 + hw] = pack2(1.f - sf, 1.f - sf2);
  }
}

// ---------------- MFMA GEMMs ----------------

// nu: C[cv][l] = qvm16[bn] (Cv x HW) . zz16[bng] (HW x L); epilogue -> mv2 bf16
__global__ __launch_bounds__(256) void k_nu(const short* __restrict__ qvm16, const short* __restrict__ zz16,
                                            const float* __restrict__ nu0, const float* __restrict__ zita0,
                                            const float* __restrict__ zita, short* __restrict__ mv2){
  constexpr int AP = 40;
  __shared__ short lA[64*AP];
  __shared__ short lB[64*AP];
  int blk = blockIdx.x;                  // 512 = 16 bng * 8 cvb * 4 lb
  int bng = blk >> 5, cvb = (blk >> 2) & 7, lb = blk & 3;
  int bn = bng >> 1, g = bng & 1;
  int t = threadIdx.x, lane = t & 63, w = t >> 6;
  int wm = w >> 1, wn = w & 1;
  int quad = lane >> 4, fr = lane & 15;
  f32x4 acc[2][2] = {};
  const short* Ab = qvm16 + ((size_t)bn*512 + cvb*64)*4096;
  const short* Bb = zz16 + (size_t)bng*4096*256 + lb*64;
  int arow = t >> 2, acg = (t & 3)*8;
  int bhw = t & 31, blg = (t >> 5)*8;
  for (int k0 = 0; k0 < 4096; k0 += 32){
    __syncthreads();
    *(bf16x8*)&lA[arow*AP + acg] = *(const bf16x8*)(Ab + (size_t)arow*4096 + k0 + acg);
    {
      bf16x8 v = *(const bf16x8*)(Bb + (size_t)(k0 + bhw)*256 + blg);
      #pragma unroll
      for (int j=0;j<8;j++) lB[(blg+j)*AP + bhw] = v[j];
    }
    __syncthreads();
    int koff = quad*8;
    bf16x8 a0 = *(const bf16x8*)&lA[(wm*32 +  0 + fr)*AP + koff];
    bf16x8 a1 = *(const bf16x8*)&lA[(wm*32 + 16 + fr)*AP + koff];
    bf16x8 b0 = *(const bf16x8*)&lB[(wn*32 +  0 + fr)*AP + koff];
    bf16x8 b1 = *(const bf16x8*)&lB[(wn*32 + 16 + fr)*AP + koff];
    acc[0][0] = __builtin_amdgcn_mfma_f32_16x16x32_bf16(a0,b0,acc[0][0],0,0,0);
    acc[0][1] = __builtin_amdgcn_mfma_f32_16x16x32_bf16(a0,b1,acc[0][1],0,0,0);
    acc[1][0] = __builtin_amdgcn_mfma_f32_16x16x32_bf16(a1,b0,acc[1][0],0,0,0);
    acc[1][1] = __builtin_amdgcn_mfma_f32_16x16x32_bf16(a1,b1,acc[1][1],0,0,0);
  }
  #pragma unroll
  for (int mf=0; mf<2; mf++)
  #pragma unroll
  for (int nf=0; nf<2; nf++)
  #pragma unroll
  for (int r=0;r<4;r++){
    int cv = cvb*64 + wm*32 + mf*16 + quad*4 + r;
    int l  = lb*64 + wn*32 + nf*16 + fr;
    float c = acc[mf][nf][r];
    float z0 = zita0[bng*256 + l];
    float nv = (z0 * nu0[((size_t)bng*512 + cv)*256 + l] + c) / zita[bng*256 + l];
    mv2[((size_t)bn*512 + cv)*512 + g*256 + l] = f2b(nv);
  }
}

// mem_out: C[cv][hw] = mv2[bn] (Cv x 2L) . paff16[bn] (2L x HW) -> fin32 pairs [0,256)
__global__ __launch_bounds__(256) void k_mem(const short* __restrict__ mv2, const short* __restrict__ paff16,
                                             unsigned* __restrict__ fin32){
  constexpr int BP = 40;
  __shared__ short lB[256*BP];
  int blk = blockIdx.x;                  // 1024 = 8 bn * 8 cvb * 16 hwb
  int bn = blk >> 7, cvb = (blk >> 4) & 7, hwb = blk & 15;
  int t = threadIdx.x, lane = t & 63, w = t >> 6;
  int quad = lane >> 4, fr = lane & 15;
  f32x4 acc[4][4] = {};
  const short* Ab = mv2 + ((size_t)bn*512 + cvb*64)*512;
  const short* Bb = paff16 + ((size_t)bn*4096 + hwb*256)*512;
  for (int k0=0; k0<512; k0+=32){
    __syncthreads();
    {
      const short* s = Bb + (size_t)t*512 + k0;
      #pragma unroll
      for (int q=0;q<4;q++)
        *(bf16x8*)&lB[t*BP + q*8] = *(const bf16x8*)(s + q*8);
    }
    __syncthreads();
    int koff = quad*8;
    bf16x8 af[4];
    #pragma unroll
    for (int mf=0; mf<4; mf++)
      af[mf] = *(const bf16x8*)(Ab + (size_t)(mf*16 + fr)*512 + k0 + koff);
    #pragma unroll
    for (int nf=0; nf<4; nf++){
      bf16x8 bv = *(const bf16x8*)&lB[(w*64 + nf*16 + fr)*BP + koff];
      #pragma unroll
      for (int mf=0; mf<4; mf++)
        acc[mf][nf] = __builtin_amdgcn_mfma_f32_16x16x32_bf16(af[mf], bv, acc[mf][nf],0,0,0);
    }
  }
  #pragma unroll
  for (int mf=0;mf<4;mf++)
  #pragma unroll
  for (int nf=0;nf<4;nf++){
    int hw = hwb*256 + w*64 + nf*16 + fr;
    int p0 = cvb*32 + mf*8 + quad*2;
    unsigned lo = pack2(acc[mf][nf][0], acc[mf][nf][1]);
    unsigned hi = pack2(acc[mf][nf][2], acc[mf][nf][3]);
    fin32[(size_t)bn*2359296 + (size_t)p0*4096 + hw] = lo;
    fin32[(size_t)bn*2359296 + (size_t)(p0+1)*4096 + hw] = hi;
  }
}

// single conv (F or A), 32x32x16 MFMA, K-chunk 16 ch. Wave = 64cv x (2y x 64x).
// Weights global->VGPR with next-r9 prefetch; im2col staging prefetched across cb.
// gate=0: dst = raw + bias (f scratch). gate=1: dst = fsrc * sigmoid(raw + bias).
__global__ __launch_bounds__(256, 2) void k_conv(const unsigned* __restrict__ fin32,
                                                 const short* __restrict__ Wt,
                                                 const float* __restrict__ bias,
                                                 const float* __restrict__ fsrc,
                                                 float* __restrict__ dst, int gate){
  __shared__ unsigned lFu[2*10*66*4];    // [kh][row 10][px 66][pj 4]
  int blk = blockIdx.x;                  // 512 = 8 bn * 8 cvb * 8 yb
  int bn = blk >> 6, cvb = (blk >> 3) & 7, yb = blk & 7;
  int t = threadIdx.x, lane = t & 63, w = t >> 6;
  int ln = lane & 31, kh = lane >> 5;
  int y0 = yb*8;
  f32x16 acc[2][2][2] = {};              // [mf][ly][xh] = 128 AGPR
  const unsigned* finB = fin32 + (size_t)bn*2359296;
  if (t < 160){
    int pj = t & 3, side = (t>>2)&1, row = (t>>3)%10, khz = t/80;
    lFu[((khz*10 + row)*66 + (side?65:0))*4 + pj] = 0u;
  }
  const short* WB = Wt + (size_t)cvb*663552 + kh*512 + ln*8;
  int sx = t & 63, q = t >> 6;
  unsigned stg[20];
  #pragma unroll
  for (int i=0;i<20;i++){
    int id = q*20+i; int row = id>>3; int p8 = id&7;
    int gy = y0 - 1 + row;
    unsigned v = 0u;
    if (gy>=0 && gy<64) v = finB[(size_t)p8*4096 + gy*64 + sx];
    stg[i] = v;
  }
  bf16x8 w0 = *(const bf16x8*)(WB);
  bf16x8 w1 = *(const bf16x8*)(WB + 256);
  for (int cb=0; cb<72; cb++){
    __syncthreads();
    #pragma unroll
    for (int i=0;i<20;i++){
      int id = q*20+i; int row = id>>3; int p8 = id&7;
      lFu[(((p8>>2)*10 + row)*66 + sx + 1)*4 + (p8&3)] = stg[i];
    }
    __syncthreads();
    if (cb < 71){
      #pragma unroll
      for (int i=0;i<20;i++){
        int id = q*20+i; int row = id>>3; int p8 = id&7;
        int gy = y0 - 1 + row;
        unsigned v = 0u;
        if (gy>=0 && gy<64) v = finB[(size_t)((cb+1)*8 + p8)*4096 + gy*64 + sx];
        stg[i] = v;
      }
    }
    const short* wc = WB + cb*9216;
    #pragma unroll
    for (int r9=0; r9<9; r9++){
      int dy = r9/3, dx = r9 - dy*3;
      bf16x8 cw0 = w0, cw1 = w1;
      const short* wn = (r9<8) ? (wc + (r9+1)*1024) : (WB + (cb+1)*9216);
      w0 = *(const bf16x8*)(wn);
      w1 = *(const bf16x8*)(wn + 256);
      #pragma unroll
      for (int ly=0; ly<2; ly++){
        int row = w*2 + ly + dy;
        #pragma unroll
        for (int xh=0; xh<2; xh++){
          bf16x8 bv = *(const bf16x8*)((const short*)lFu + ((size_t)((kh*10 + row)*66 + xh*32 + ln + dx))*8);
          acc[0][ly][xh] = __builtin_amdgcn_mfma_f32_32x32x16_bf16(cw0, bv, acc[0][ly][xh],0,0,0);
          acc[1][ly][xh] = __builtin_amdgcn_mfma_f32_32x32x16_bf16(cw1, bv, acc[1][ly][xh],0,0,0);
        }
      }
    }
  }
  #pragma unroll
  for (int mf=0; mf<2; mf++)
  #pragma unroll
  for (int ly=0; ly<2; ly++)
  #pragma unroll
  for (int xh=0; xh<2; xh++){
    int y = y0 + w*2 + ly;
    int x = xh*32 + ln;
    #pragma unroll
    for (int reg=0; reg<16; reg++){
      int cv = cvb*64 + mf*32 + 4*kh + 8*(reg>>2) + (reg&3);
      float v = acc[mf][ly][xh][reg] + bias[cv];
      size_t oidx = ((size_t)bn*512 + cv)*4096 + (size_t)y*64 + x;
      if (gate){
        float fv = fsrc[oidx];
        dst[oidx] = fv/(1.f + __expf(-v));
      } else {
        dst[oidx] = v;
      }
    }
  }
}

// ---------------- launch ----------------

extern "C" void kernel_launch(void* const* d_in, const int* in_sizes, int n_in,
                              void* d_out, int out_size, void* d_ws, size_t ws_size,
                              hipStream_t stream){
  const float* qk     = (const float*)d_in[0];
  const float* qv     = (const float*)d_in[1];
  const float* qvm    = (const float*)d_in[2];
  const float* masks  = (const float*)d_in[3];
  const float* kappa0 = (const float*)d_in[4];
  const float* nu0    = (const float*)d_in[5];
  const float* zita0  = (const float*)d_in[6];
  const float* Wf     = (const float*)d_in[7];
  const float* bfb    = (const float*)d_in[8];
  const float* Wa     = (const float*)d_in[9];
  const float* bab    = (const float*)d_in[10];
  float* out = (float*)d_out;

  float* ws    = (float*)d_ws;
  float* xT    = ws;                          // 524,288 f
  float* invn  = xT + 524288;                 // 8,192 f
  float* kn    = invn + 8192;                 // 262,144 f
  float* zita  = kn + 262144;                 // 4,096 f
  float* zpart = zita + 4096;                 // 131,072 f
  float* kpart = zpart + 131072;              // 8,388,608 f (aliased by paff16 after EM)
  short* paff16 = (short*)kpart;              // 16,777,216 s
  short* mv2   = (short*)(kpart + 8388608);   // 4,194,304 s
  unsigned* fin32 = (unsigned*)(mv2 + 4194304);   // 18,874,368 u32
  short* Wtf   = (short*)(fin32 + 18874368);  // 5,308,416 s
  short* Wta   = Wtf + 5308416;               // 5,308,416 s
  short* qvm16 = Wta + 5308416;               // 16,777,216 s \ aliased by f_scr after k_nu
  short* zz16  = qvm16 + 16777216;            // 16,777,216 s /
  float* f_scr = (float*)qvm16;               // 16,777,216 f

  k_prep_x<<<32, 256, 0, stream>>>(qk, xT, invn);
  k_init_kn<<<16, 256, 0, stream>>>(kappa0, kn);
  k_prep_wt<<<20736, 256, 0, stream>>>(Wf, Wtf);
  k_prep_wt<<<20736, 256, 0, stream>>>(Wa, Wta);
  k_qv_fin<<<32768, 256, 0, stream>>>(qv, fin32);
  k_qvm16<<<16384, 256, 0, stream>>>(qvm, (unsigned*)qvm16);

  for (int it = 0; it < 4; ++it){
    k_em<<<256, 512, 0, stream>>>(xT, kn, masks, invn, kpart, zpart, zz16,
                                  it==0 ? 1 : 0, it==3 ? 1 : 0);
    k_fin<<<64, 256, 0, stream>>>(kpart, zpart, kappa0, zita0, kn, zita);
  }

  k_nu<<<512, 256, 0, stream>>>(qvm16, zz16, nu0, zita0, zita, mv2);
  k_aff<<<256, 512, 0, stream>>>(xT, kn, invn, paff16);
  k_topk<<<8192, 256, 0, stream>>>(paff16, fin32);
  k_mem<<<1024, 256, 0, stream>>>(mv2, paff16, fin32);
  k_conv<<<512, 256, 0, stream>>>(fin32, Wtf, bfb, nullptr, f_scr, 0);
  k_conv<<<512, 256, 0, stream>>>(fin32, Wta, bab, f_scr, out, 1);
}